// Round 23
// baseline (911.159 us; speedup 1.0000x reference)
//
#include <hip/hip_runtime.h>

// ---------------------------------------------------------------------------
// HeteroGNN (2-layer hetero GAT) forward on MI355X — round 23.
// vs round 22 (passed, 910us): edge_fused gets wave-private REG-STAGED
// PREFETCH (issue next tile's global loads before computing current tile,
// ds_write after compute; single LDS buffer, no barriers). r22 counters
// showed the kernel stalls ~600cyc on HBM latency before every 32-edge tile
// (VALU 47%, occupancy-insensitive). +8 VGPR, under the (256,3) cap.
// Everything else identical to round 22.
// ---------------------------------------------------------------------------

static constexpr int NPn = 150000;
static constexpr int NBn = 250000;
static constexpr int En  = 500000;

static constexpr int OFF_PP = 0;
static constexpr int OFF_BP = 150016;
static constexpr int OFF_BB = 300032;
static constexpr int NCAT   = 550144;
static constexpr int NB_TOT = NCAT / 256;
static constexpr int BS_BP  = OFF_BP / 256;
static constexpr int BS_BB  = OFF_BB / 256;

__device__ __forceinline__ float lrelu(float x, float s) { return x >= 0.0f ? x : s * x; }

__global__ void fill_kernel(float* out, float val, int n) {
  int i = blockIdx.x * blockDim.x + threadIdx.x;
  if (i < n) out[i] = val;
}

// ---------------- batched CSR build ----------------
struct Dsts { const int* d[3]; const int* s[3]; };

__global__ void zero_int_kernel(int* p, int n) {
  int i = blockIdx.x * blockDim.x + threadIdx.x;
  if (i < n) p[i] = 0;
}

__global__ void hist_all_kernel(Dsts ds, int* __restrict__ cnt) {
  int t = blockIdx.x * blockDim.x + threadIdx.x;
  if (t >= 3 * En) return;
  int rel = t / En, e = t - rel * En;
  int base = (rel == 0) ? OFF_PP : (rel == 1) ? OFF_BP : OFF_BB;
  atomicAdd(&cnt[base + ds.d[rel][e]], 1);
}

__global__ void scan1_kernel(const int* __restrict__ cnt, int* __restrict__ incl,
                             int* __restrict__ bsum, int n) {
  __shared__ int s[256];
  int i = blockIdx.x * 256 + threadIdx.x;
  s[threadIdx.x] = (i < n) ? cnt[i] : 0;
  __syncthreads();
  for (int o = 1; o < 256; o <<= 1) {
    int t = (threadIdx.x >= o) ? s[threadIdx.x - o] : 0;
    __syncthreads();
    s[threadIdx.x] += t;
    __syncthreads();
  }
  if (i < n) incl[i] = s[threadIdx.x];
  if (threadIdx.x == 255) bsum[blockIdx.x] = s[255];
}

// parallel exclusive scan of block sums, one block per segment
__global__ void scan2_kernel(int* bsum) {
  int seg = blockIdx.x;
  int lo = (seg == 0) ? 0 : (seg == 1) ? BS_BP : BS_BB;
  int hi = (seg == 0) ? BS_BP : (seg == 1) ? BS_BB : NB_TOT;
  int len = hi - lo;
  int chunk = (len + 255) / 256;
  int s = lo + threadIdx.x * chunk;
  int e = min(s + chunk, hi);
  __shared__ int part[256];
  int sum = 0;
  for (int i = s; i < e; ++i) sum += bsum[i];
  part[threadIdx.x] = sum;
  __syncthreads();
  for (int o = 1; o < 256; o <<= 1) {
    int t = (threadIdx.x >= o) ? part[threadIdx.x - o] : 0;
    __syncthreads();
    part[threadIdx.x] += t;
    __syncthreads();
  }
  int run = (threadIdx.x == 0) ? 0 : part[threadIdx.x - 1];
  for (int i = s; i < e; ++i) { int v = bsum[i]; bsum[i] = run; run += v; }
}

__global__ void scan3_kernel(const int* __restrict__ cnt, int* __restrict__ offs,
                             const int* __restrict__ bsum, int n) {
  int i = blockIdx.x * 256 + threadIdx.x;
  if (i < n) offs[i] = offs[i] - cnt[i] + bsum[i >> 8];
}

__global__ void copy_int_kernel(const int* __restrict__ src, int* __restrict__ dstp, int n) {
  int i = blockIdx.x * blockDim.x + threadIdx.x;
  if (i < n) dstp[i] = src[i];
}

__global__ void scatter_all_kernel(Dsts ds, int* __restrict__ cursor,
                                   int* __restrict__ srcs, int* __restrict__ pos) {
  int t = blockIdx.x * blockDim.x + threadIdx.x;
  if (t >= 3 * En) return;
  int rel = t / En, e = t - rel * En;
  int base = (rel == 0) ? OFF_PP : (rel == 1) ? OFF_BP : OFF_BB;
  int p = atomicAdd(&cursor[base + ds.d[rel][e]], 1);
  srcs[rel * En + p] = ds.s[rel][e];
  pos[rel * En + e] = p;
}

// ---------------- tiled dense kernels (r20, proven) ----------------
__global__ void proj_kernel(const float* __restrict__ X, const float* __restrict__ W,
                            const float* __restrict__ b, float* __restrict__ Y, int N) {
  __shared__ __align__(16) float Ws[32 * 64];
  __shared__ float Xs[64 * 33];
  __shared__ float bs[64];
  for (int i = threadIdx.x; i < 32 * 64; i += 256) Ws[i] = W[i];
  if (threadIdx.x < 64) bs[threadIdx.x] = b[threadIdx.x];
  int base = blockIdx.x * 64;
  int rows = min(64, N - base);
  {
    const float4* s4 = reinterpret_cast<const float4*>(X + (size_t)base * 32);
    for (int idx = threadIdx.x; idx < rows * 8; idx += 256) {
      float4 v = s4[idx];
      int r = idx >> 3, c4 = idx & 7;
      float* d = &Xs[r * 33 + c4 * 4];
      d[0] = v.x; d[1] = v.y; d[2] = v.z; d[3] = v.w;
    }
  }
  __syncthreads();
  int r = threadIdx.x >> 2, q = threadIdx.x & 3;
  if (r >= rows) return;
  const float4* Ws4 = reinterpret_cast<const float4*>(Ws);
  float acc[16];
  const float4* b4 = reinterpret_cast<const float4*>(&bs[q * 16]);
#pragma unroll
  for (int j = 0; j < 4; ++j) {
    float4 v = b4[j];
    acc[4 * j + 0] = v.x; acc[4 * j + 1] = v.y; acc[4 * j + 2] = v.z; acc[4 * j + 3] = v.w;
  }
#pragma unroll
  for (int k = 0; k < 32; ++k) {
    float xv = Xs[r * 33 + k];
#pragma unroll
    for (int j = 0; j < 4; ++j) {
      float4 w = Ws4[k * 16 + q * 4 + j];
      acc[4 * j + 0] += xv * w.x; acc[4 * j + 1] += xv * w.y;
      acc[4 * j + 2] += xv * w.z; acc[4 * j + 3] += xv * w.w;
    }
  }
  float4* y4 = reinterpret_cast<float4*>(Y + (size_t)(base + r) * 64 + q * 16);
#pragma unroll
  for (int j = 0; j < 4; ++j)
    y4[j] = make_float4(lrelu(acc[4 * j + 0], 0.01f), lrelu(acc[4 * j + 1], 0.01f),
                        lrelu(acc[4 * j + 2], 0.01f), lrelu(acc[4 * j + 3], 0.01f));
}

__global__ void hgemm_kernel(const float* X, const float* __restrict__ W,
                             const float* __restrict__ a1, const float* __restrict__ a2,
                             const float* __restrict__ xv,
                             float* H, float* __restrict__ S1,
                             float* __restrict__ S2, float* __restrict__ S3, int N) {
  __shared__ __align__(16) float Ws[64 * 64];
  __shared__ float Xs[64 * 65];
  __shared__ float a1s[64], a2s[64], xvs[64];
  for (int i = threadIdx.x; i < 64 * 64; i += 256) Ws[i] = W[i];
  if (threadIdx.x < 64) {
    a1s[threadIdx.x] = a1[threadIdx.x];
    a2s[threadIdx.x] = a2 ? a2[threadIdx.x] : 0.0f;
    xvs[threadIdx.x] = xv ? xv[threadIdx.x] : 0.0f;
  }
  int base = blockIdx.x * 64;
  int rows = min(64, N - base);
  {
    const float4* s4 = reinterpret_cast<const float4*>(X + (size_t)base * 64);
    for (int idx = threadIdx.x; idx < rows * 16; idx += 256) {
      float4 v = s4[idx];
      int r = idx >> 4, c4 = idx & 15;
      float* d = &Xs[r * 65 + c4 * 4];
      d[0] = v.x; d[1] = v.y; d[2] = v.z; d[3] = v.w;
    }
  }
  __syncthreads();
  int r = threadIdx.x >> 2, q = threadIdx.x & 3;
  if (r >= rows) return;
  const float4* Ws4 = reinterpret_cast<const float4*>(Ws);
  float acc[16];
#pragma unroll
  for (int c = 0; c < 16; ++c) acc[c] = 0.0f;
  float s3p = 0.0f;
#pragma unroll
  for (int k = 0; k < 64; ++k) {
    float xval = Xs[r * 65 + k];
#pragma unroll
    for (int j = 0; j < 4; ++j) {
      float4 w = Ws4[k * 16 + q * 4 + j];
      acc[4 * j + 0] += xval * w.x; acc[4 * j + 1] += xval * w.y;
      acc[4 * j + 2] += xval * w.z; acc[4 * j + 3] += xval * w.w;
    }
  }
#pragma unroll
  for (int k = 0; k < 16; ++k) s3p += Xs[r * 65 + q * 16 + k] * xvs[q * 16 + k];
  float s1p = 0.0f, s2p = 0.0f;
#pragma unroll
  for (int c = 0; c < 16; ++c) {
    s1p += acc[c] * a1s[q * 16 + c];
    s2p += acc[c] * a2s[q * 16 + c];
  }
  s1p += __shfl_xor(s1p, 1, 64); s1p += __shfl_xor(s1p, 2, 64);
  s2p += __shfl_xor(s2p, 1, 64); s2p += __shfl_xor(s2p, 2, 64);
  s3p += __shfl_xor(s3p, 1, 64); s3p += __shfl_xor(s3p, 2, 64);
  float4* h4 = reinterpret_cast<float4*>(H + (size_t)(base + r) * 64 + q * 16);
#pragma unroll
  for (int j = 0; j < 4; ++j)
    h4[j] = make_float4(acc[4 * j + 0], acc[4 * j + 1], acc[4 * j + 2], acc[4 * j + 3]);
  if (q == 0) {
    S1[base + r] = s1p;
    if (S2) S2[base + r] = s2p;
    if (S3) S3[base + r] = s3p;
  }
}

__global__ void hgemm2_kernel(float* X, const float* __restrict__ W1,
                              const float* __restrict__ a1a,
                              const float* __restrict__ W2,
                              const float* __restrict__ a2a, const float* __restrict__ a2b,
                              float* __restrict__ H1out,
                              float* __restrict__ S1a, float* __restrict__ S2a,
                              float* __restrict__ S2b, int N) {
  __shared__ __align__(16) float W1s[64 * 64];
  __shared__ __align__(16) float W2s[64 * 64];
  __shared__ float Xs[64 * 65];
  __shared__ float v1[64], v2a[64], v2b[64];
  for (int i = threadIdx.x; i < 64 * 64; i += 256) { W1s[i] = W1[i]; W2s[i] = W2[i]; }
  if (threadIdx.x < 64) {
    v1[threadIdx.x] = a1a[threadIdx.x];
    v2a[threadIdx.x] = a2a[threadIdx.x];
    v2b[threadIdx.x] = a2b[threadIdx.x];
  }
  int base = blockIdx.x * 64;
  int rows = min(64, N - base);
  {
    const float4* s4 = reinterpret_cast<const float4*>(X + (size_t)base * 64);
    for (int idx = threadIdx.x; idx < rows * 16; idx += 256) {
      float4 v = s4[idx];
      int r = idx >> 4, c4 = idx & 15;
      float* d = &Xs[r * 65 + c4 * 4];
      d[0] = v.x; d[1] = v.y; d[2] = v.z; d[3] = v.w;
    }
  }
  __syncthreads();
  int r = threadIdx.x >> 2, q = threadIdx.x & 3;
  if (r >= rows) return;
  const float4* W1s4 = reinterpret_cast<const float4*>(W1s);
  const float4* W2s4 = reinterpret_cast<const float4*>(W2s);
  float acc1[16], acc2[16];
#pragma unroll
  for (int c = 0; c < 16; ++c) { acc1[c] = 0.0f; acc2[c] = 0.0f; }
#pragma unroll
  for (int k = 0; k < 64; ++k) {
    float xval = Xs[r * 65 + k];
#pragma unroll
    for (int j = 0; j < 4; ++j) {
      float4 w1 = W1s4[k * 16 + q * 4 + j];
      acc1[4 * j + 0] += xval * w1.x; acc1[4 * j + 1] += xval * w1.y;
      acc1[4 * j + 2] += xval * w1.z; acc1[4 * j + 3] += xval * w1.w;
      float4 w2 = W2s4[k * 16 + q * 4 + j];
      acc2[4 * j + 0] += xval * w2.x; acc2[4 * j + 1] += xval * w2.y;
      acc2[4 * j + 2] += xval * w2.z; acc2[4 * j + 3] += xval * w2.w;
    }
  }
  float s1p = 0.0f, sap = 0.0f, sbp = 0.0f;
#pragma unroll
  for (int c = 0; c < 16; ++c) {
    s1p += acc1[c] * v1[q * 16 + c];
    sap += acc2[c] * v2a[q * 16 + c];
    sbp += acc2[c] * v2b[q * 16 + c];
  }
  s1p += __shfl_xor(s1p, 1, 64); s1p += __shfl_xor(s1p, 2, 64);
  sap += __shfl_xor(sap, 1, 64); sap += __shfl_xor(sap, 2, 64);
  sbp += __shfl_xor(sbp, 1, 64); sbp += __shfl_xor(sbp, 2, 64);
  float4* h14 = reinterpret_cast<float4*>(H1out + (size_t)(base + r) * 64 + q * 16);
  float4* h24 = reinterpret_cast<float4*>(X + (size_t)(base + r) * 64 + q * 16);
#pragma unroll
  for (int j = 0; j < 4; ++j) {
    h14[j] = make_float4(acc1[4 * j + 0], acc1[4 * j + 1], acc1[4 * j + 2], acc1[4 * j + 3]);
    h24[j] = make_float4(acc2[4 * j + 0], acc2[4 * j + 1], acc2[4 * j + 2], acc2[4 * j + 3]);
  }
  if (q == 0) {
    S1a[base + r] = s1p;
    S2a[base + r] = sap;
    S2b[base + r] = sbp;
  }
}

struct RowdotJobs { const float* M[7]; const float* v[7]; float* out[7]; };
__global__ void rowdot_batch_kernel(RowdotJobs J) {
  __shared__ float vs[64];
  int j = blockIdx.x;
  vs[threadIdx.x] = J.v[j][threadIdx.x];
  __syncthreads();
  float s = 0.0f;
  const float* M = J.M[j];
#pragma unroll
  for (int c = 0; c < 64; ++c) s += M[threadIdx.x * 64 + c] * vs[c];
  J.out[j][threadIdx.x] = s;
}

// ---------------- quarter-wave edge kernel, reg-staged prefetch --------------
struct EdgeJobs {
  const float* EA[3]; const float* We[3]; const float* be[3];
  const float* wa1[3]; const float* wa2[3]; float* hd1[3]; float* hd2[3];
  const int* pos[3];
};
__global__ __launch_bounds__(256, 3) void edge_fused_kernel(EdgeJobs J,
                                                            float* __restrict__ sacc) {
  int rel = blockIdx.x >> 9;
  int blk = blockIdx.x & 511;
  __shared__ float eas[4][32 * 16];
  __shared__ float red1[4], red2[4];
  bool has2 = (J.wa2[rel] != nullptr);
  int lane = threadIdx.x & 63;
  int wv   = threadIdx.x >> 6;
  int qd   = lane >> 4;
  int sl   = lane & 15;
  float* myeas = eas[wv];
  float4* d4 = reinterpret_cast<float4*>(myeas);
  float wreg[16][4];
  const float* We = J.We[rel];
#pragma unroll
  for (int k = 0; k < 16; ++k) {
    float4 w = *reinterpret_cast<const float4*>(&We[k * 64 + sl * 4]);
    wreg[k][0] = w.x; wreg[k][1] = w.y; wreg[k][2] = w.z; wreg[k][3] = w.w;
  }
  float4 bc = *reinterpret_cast<const float4*>(&J.be[rel][sl * 4]);
  float4 w1c = *reinterpret_cast<const float4*>(&J.wa1[rel][sl * 4]);
  float4 w2c = has2 ? *reinterpret_cast<const float4*>(&J.wa2[rel][sl * 4])
                    : make_float4(0.f, 0.f, 0.f, 0.f);
  const float* EA = J.EA[rel];
  float* hd1 = J.hd1[rel];
  float* hd2 = J.hd2[rel];
  const int* pos = J.pos[rel];
  float s1 = 0.0f, s2 = 0.0f;
  const int STRIDE = 512 * 4 * 32;
  int base0 = (blk * 4 + wv) * 32;
  // prologue: stage tile 0
  if (base0 < En) {
    int tl4 = min(32, En - base0) * 4;
    const float4* s4 = reinterpret_cast<const float4*>(EA + (size_t)base0 * 16);
    float4 a = (lane < tl4) ? s4[lane] : make_float4(0.f, 0.f, 0.f, 0.f);
    float4 b = (64 + lane < tl4) ? s4[64 + lane] : make_float4(0.f, 0.f, 0.f, 0.f);
    d4[lane] = a;
    d4[64 + lane] = b;
  }
  for (int base = base0; base < En; base += STRIDE) {
    // issue next tile's global loads BEFORE computing current tile
    int nb = base + STRIDE;
    bool nv = nb < En;
    float4 n0 = make_float4(0.f, 0.f, 0.f, 0.f), n1 = n0;
    if (nv) {
      int tl4 = min(32, En - nb) * 4;
      const float4* s4n = reinterpret_cast<const float4*>(EA + (size_t)nb * 16);
      if (lane < tl4) n0 = s4n[lane];
      if (64 + lane < tl4) n1 = s4n[64 + lane];
    }
    int tile = min(32, En - base);
#pragma unroll
    for (int it = 0; it < 8; ++it) {
      int e = it * 4 + qd;
      if (e < tile) {
        float t0 = bc.x, t1 = bc.y, t2 = bc.z, t3 = bc.w;
#pragma unroll
        for (int k = 0; k < 16; ++k) {
          float xv = myeas[e * 16 + k];
          t0 += xv * wreg[k][0]; t1 += xv * wreg[k][1];
          t2 += xv * wreg[k][2]; t3 += xv * wreg[k][3];
        }
        t0 = lrelu(t0, 0.01f); t1 = lrelu(t1, 0.01f);
        t2 = lrelu(t2, 0.01f); t3 = lrelu(t3, 0.01f);
        float d1 = t0 * w1c.x + t1 * w1c.y + t2 * w1c.z + t3 * w1c.w;
        float d2 = t0 * w2c.x + t1 * w2c.y + t2 * w2c.z + t3 * w2c.w;
#pragma unroll
        for (int o = 1; o < 16; o <<= 1) {
          d1 += __shfl_xor(d1, o, 64);
          d2 += __shfl_xor(d2, o, 64);
        }
        if (sl == 0) {
          int p = pos[base + e];
          hd1[p] = d1;
          if (has2) hd2[p] = d2;
          s1 += d1;
          s2 += d2;
        }
      }
    }
    // write prefetched tile AFTER compute (same-wave ds ordering; loads had
    // the whole compute window to land)
    if (nv) {
      d4[lane] = n0;
      d4[64 + lane] = n1;
    }
  }
  if (rel < 2) {
#pragma unroll
    for (int o = 32; o >= 1; o >>= 1) {
      s1 += __shfl_xor(s1, o, 64);
      s2 += __shfl_xor(s2, o, 64);
    }
    if (lane == 0) { red1[wv] = s1; red2[wv] = s2; }
    __syncthreads();
    if (threadIdx.x == 0) {
      float t1 = red1[0] + red1[1] + red1[2] + red1[3];
      float t2 = red2[0] + red2[1] + red2[2] + red2[3];
      if (rel == 0) {
        atomicAdd(&sacc[0], t1);
        atomicAdd(&sacc[1], t2);
      } else {
        atomicAdd(&sacc[2], t1);
      }
    }
  }
}

__global__ void selfscale_kernel(const float* __restrict__ sacc, float invE,
                                 float* __restrict__ self_pp1, float* __restrict__ self_pp2,
                                 float* __restrict__ self_bb1) {
  if (threadIdx.x == 0) {
    self_pp1[0] = sacc[0] * invE;
    self_pp2[0] = sacc[1] * invE;
    self_bb1[0] = sacc[2] * invE;
  }
}

// ---------------- fused per-row GAT kernels ----------------
__global__ void gat_row_kernel(const int* __restrict__ offs, const int* __restrict__ srcs,
                               const float* __restrict__ ssrc, const float* __restrict__ sdst,
                               const float* __restrict__ hd, const float* __restrict__ selfhd,
                               const float* __restrict__ H, const float* __restrict__ bias,
                               float* __restrict__ out, int N) {
  int wid = (int)(((size_t)blockIdx.x * blockDim.x + threadIdx.x) >> 6);
  int lane = threadIdx.x & 63;
  if (wid >= N) return;
  int lo = offs[wid], hi = offs[wid + 1];
  float sd = sdst[wid];
  float wsum = 1e-16f;
  float acc = 0.0f;
  if (selfhd) {
    float wself = __expf(lrelu(ssrc[wid] + sd + selfhd[0], 0.2f));
    wsum += wself;
    acc = wself * H[(size_t)wid * 64 + lane];
  }
#pragma unroll 2
  for (int p = lo; p < hi; ++p) {
    int s = srcs[p];
    float w = __expf(lrelu(ssrc[s] + sd + hd[p], 0.2f));
    wsum += w;
    acc += w * H[(size_t)s * 64 + lane];
  }
  out[(size_t)wid * 64 + lane] = acc / wsum + bias[lane];
}

__global__ void gat_row2_kernel(
    const int* __restrict__ offsA, const int* __restrict__ srcsA,
    const float* __restrict__ ssrcA, const float* __restrict__ sdstA,
    const float* __restrict__ hdA, const float* __restrict__ selfhdA,
    const float* __restrict__ HA, const float* __restrict__ biasA,
    const int* __restrict__ offsB, const int* __restrict__ srcsB,
    const float* __restrict__ ssrcB, const float* __restrict__ sdstB,
    const float* __restrict__ hdB, const float* __restrict__ HB,
    const float* __restrict__ biasB,
    float* __restrict__ out, int N) {
  int wid = (int)(((size_t)blockIdx.x * blockDim.x + threadIdx.x) >> 6);
  int lane = threadIdx.x & 63;
  if (wid >= N) return;
  int lo = offsA[wid], hi = offsA[wid + 1];
  float sd = sdstA[wid];
  float wself = __expf(lrelu(ssrcA[wid] + sd + selfhdA[0], 0.2f));
  float wsumA = 1e-16f + wself;
  float accA = wself * HA[(size_t)wid * 64 + lane];
#pragma unroll 2
  for (int p = lo; p < hi; ++p) {
    int s = srcsA[p];
    float w = __expf(lrelu(ssrcA[s] + sd + hdA[p], 0.2f));
    wsumA += w;
    accA += w * HA[(size_t)s * 64 + lane];
  }
  lo = offsB[wid]; hi = offsB[wid + 1];
  float sdB = sdstB[wid];
  float wsumB = 1e-16f;
  float accB = 0.0f;
#pragma unroll 2
  for (int p = lo; p < hi; ++p) {
    int s = srcsB[p];
    float w = __expf(lrelu(ssrcB[s] + sdB + hdB[p], 0.2f));
    wsumB += w;
    accB += w * HB[(size_t)s * 64 + lane];
  }
  out[(size_t)wid * 64 + lane] =
      accA / wsumA + biasA[lane] + accB / wsumB + biasB[lane];
}

__global__ void gat_row2h_kernel(
    const int* __restrict__ offsA, const int* __restrict__ srcsA,
    const float* __restrict__ ssrcA, const float* __restrict__ sdstA,
    const float* __restrict__ hdA, const float* __restrict__ selfhdA,
    const float* __restrict__ HA, const float* __restrict__ biasA,
    const int* __restrict__ offsB, const int* __restrict__ srcsB,
    const float* __restrict__ ssrcB, const float* __restrict__ sdstB,
    const float* __restrict__ hdB, const float* __restrict__ HB,
    const float* __restrict__ biasB,
    const float* __restrict__ wout, const float* __restrict__ bout,
    float* __restrict__ out, int N) {
  int wid = (int)(((size_t)blockIdx.x * blockDim.x + threadIdx.x) >> 6);
  int lane = threadIdx.x & 63;
  if (wid >= N) return;
  int lo = offsA[wid], hi = offsA[wid + 1];
  float sd = sdstA[wid];
  float wself = __expf(lrelu(ssrcA[wid] + sd + selfhdA[0], 0.2f));
  float wsumA = 1e-16f + wself;
  float accA = wself * HA[(size_t)wid * 64 + lane];
#pragma unroll 2
  for (int p = lo; p < hi; ++p) {
    int s = srcsA[p];
    float w = __expf(lrelu(ssrcA[s] + sd + hdA[p], 0.2f));
    wsumA += w;
    accA += w * HA[(size_t)s * 64 + lane];
  }
  lo = offsB[wid]; hi = offsB[wid + 1];
  float sdB = sdstB[wid];
  float wsumB = 1e-16f;
  float accB = 0.0f;
#pragma unroll 2
  for (int p = lo; p < hi; ++p) {
    int s = srcsB[p];
    float w = __expf(lrelu(ssrcB[s] + sdB + hdB[p], 0.2f));
    wsumB += w;
    accB += w * HB[(size_t)s * 64 + lane];
  }
  float r = accA / wsumA + biasA[lane] + accB / wsumB + biasB[lane];
  r *= wout[lane];
#pragma unroll
  for (int o = 32; o >= 1; o >>= 1) r += __shfl_xor(r, o, 64);
  if (lane == 0) out[wid] = r + bout[0];
}

extern "C" void kernel_launch(void* const* d_in, const int* in_sizes, int n_in,
                              void* d_out, int out_size, void* d_ws, size_t ws_size,
                              hipStream_t stream) {
  dim3 B(256);
  auto cdiv = [](int a, int b) { return (a + b - 1) / b; };

  bool okmap = (n_in == 58) &&
               in_sizes[0] == NPn * 32 && in_sizes[1] == NBn * 32 &&
               in_sizes[2] == En * 16 && in_sizes[15] == 4096 &&
               in_sizes[17] == 64 && in_sizes[53] == 64 &&
               in_sizes[55] == 2 * En && in_sizes[57] == 2 * En;
  if (!okmap) {
    fill_kernel<<<cdiv(NPn, 256), B, 0, stream>>>((float*)d_out, 1000.0f, NPn);
    return;
  }

  const float* x_p  = (const float*)d_in[0];
  const float* x_b  = (const float*)d_in[1];
  const float* ea_pp = (const float*)d_in[2];
  const float* ea_bb = (const float*)d_in[3];
  const float* ea_bp = (const float*)d_in[4];
  const float* W_node_p = (const float*)d_in[5];
  const float* b_node_p = (const float*)d_in[6];
  const float* W_node_b = (const float*)d_in[7];
  const float* b_node_b = (const float*)d_in[8];
  const float* W_edge_pp = (const float*)d_in[9];
  const float* b_edge_pp = (const float*)d_in[10];
  const float* W_edge_bb = (const float*)d_in[11];
  const float* b_edge_bb = (const float*)d_in[12];
  const float* W_edge_bp = (const float*)d_in[13];
  const float* b_edge_bp = (const float*)d_in[14];
  const float* c1_pp_W = (const float*)d_in[15];
  const float* c1_pp_We = (const float*)d_in[16];
  const float* c1_pp_asrc = (const float*)d_in[17];
  const float* c1_pp_adst = (const float*)d_in[18];
  const float* c1_pp_aedge = (const float*)d_in[19];
  const float* c1_pp_bias = (const float*)d_in[20];
  const float* c1_bb_W = (const float*)d_in[21];
  const float* c1_bb_We = (const float*)d_in[22];
  const float* c1_bb_asrc = (const float*)d_in[23];
  const float* c1_bb_adst = (const float*)d_in[24];
  const float* c1_bb_aedge = (const float*)d_in[25];
  const float* c1_bb_bias = (const float*)d_in[26];
  const float* c1_bp_Wsrc = (const float*)d_in[27];
  const float* c1_bp_Wdst = (const float*)d_in[28];
  const float* c1_bp_We = (const float*)d_in[29];
  const float* c1_bp_asrc = (const float*)d_in[30];
  const float* c1_bp_adst = (const float*)d_in[31];
  const float* c1_bp_aedge = (const float*)d_in[32];
  const float* c1_bp_bias = (const float*)d_in[33];
  const float* c2_pp_W = (const float*)d_in[34];
  const float* c2_pp_We = (const float*)d_in[35];
  const float* c2_pp_asrc = (const float*)d_in[36];
  const float* c2_pp_adst = (const float*)d_in[37];
  const float* c2_pp_aedge = (const float*)d_in[38];
  const float* c2_pp_bias = (const float*)d_in[39];
  const float* c2_bp_Wsrc = (const float*)d_in[46];
  const float* c2_bp_Wdst = (const float*)d_in[47];
  const float* c2_bp_We = (const float*)d_in[48];
  const float* c2_bp_asrc = (const float*)d_in[49];
  const float* c2_bp_adst = (const float*)d_in[50];
  const float* c2_bp_aedge = (const float*)d_in[51];
  const float* c2_bp_bias = (const float*)d_in[52];
  const float* W_out = (const float*)d_in[53];
  const float* b_out = (const float*)d_in[54];
  const int* ei_pp = (const int*)d_in[55];
  const int* ei_bb = (const int*)d_in[56];
  const int* ei_bp = (const int*)d_in[57];

  // ---- workspace layout
  float* ws = (float*)d_ws;
  int* offs_cat = (int*)ws;                  // NCAT
  int* cnt_cat  = offs_cat + NCAT;           // NCAT
  int* bsum     = cnt_cat + NCAT;            // pad 2560
  int* srcs_cat = bsum + 2560;               // 3*En
  int* pos_cat  = srcs_cat + 3 * En;         // 3*En
  float* xp    = (float*)(pos_cat + 3 * En); // NPn*64
  float* p1    = xp + (size_t)NPn * 64;      // NPn*64
  float* b1v   = p1 + (size_t)NPn * 64;      // NBn*64
  float* hbuf  = b1v + (size_t)NBn * 64;     // NBn*64
  float* hd_pp1 = hbuf + (size_t)NBn * 64;   // En x5 (CSR order)
  float* hd_pp2 = hd_pp1 + En;
  float* hd_bb1 = hd_pp2 + En;
  float* hd_bp1 = hd_bb1 + En;
  float* hd_bp2 = hd_bp1 + En;
  float* sA_src = hd_bp2 + En;               // NBn
  float* sA_dst = sA_src + NBn;              // NBn
  float* sB_src = sA_dst + NBn;              // NBn
  float* sB_dst = sB_src + NBn;              // NPn
  float* sC_src = sB_dst + NPn;              // NBn
  float* sC_dst = sC_src + NBn;              // NBn
  float* small  = sC_dst + NBn;              // 1024

  const size_t NEED = (size_t)(small + 1024 - ws) * sizeof(float);
  if (ws_size < NEED) {
    fill_kernel<<<cdiv(NPn, 256), B, 0, stream>>>((float*)d_out, 500.0f, NPn);
    return;
  }

  float* sacc    = small + 0;
  float* wa_pp1  = small + 128;  float* wa_pp2  = small + 192;
  float* wa_bb1  = small + 256;  float* wa_bp1  = small + 320; float* wa_bp2 = small + 384;
  float* wd1     = small + 448;  float* wd2     = small + 512;
  float* self_pp1= small + 576;  float* self_pp2= small + 577; float* self_bb1 = small + 578;
  const float invE = 1.0f / (float)En;

  hipMemsetAsync(sacc, 0, 16 * sizeof(float), stream);

  RowdotJobs RJ;
  RJ.M[0] = c1_pp_We;  RJ.v[0] = c1_pp_aedge; RJ.out[0] = wa_pp1;
  RJ.M[1] = c2_pp_We;  RJ.v[1] = c2_pp_aedge; RJ.out[1] = wa_pp2;
  RJ.M[2] = c1_bb_We;  RJ.v[2] = c1_bb_aedge; RJ.out[2] = wa_bb1;
  RJ.M[3] = c1_bp_We;  RJ.v[3] = c1_bp_aedge; RJ.out[3] = wa_bp1;
  RJ.M[4] = c2_bp_We;  RJ.v[4] = c2_bp_aedge; RJ.out[4] = wa_bp2;
  RJ.M[5] = c1_bp_Wdst; RJ.v[5] = c1_bp_adst; RJ.out[5] = wd1;
  RJ.M[6] = c2_bp_Wdst; RJ.v[6] = c2_bp_adst; RJ.out[6] = wd2;
  rowdot_batch_kernel<<<7, 64, 0, stream>>>(RJ);

  proj_kernel<<<cdiv(NPn, 64), B, 0, stream>>>(x_p, W_node_p, b_node_p, xp, NPn);
  proj_kernel<<<cdiv(NBn, 64), B, 0, stream>>>(x_b, W_node_b, b_node_b, hbuf, NBn);

  Dsts DS;
  DS.d[0] = ei_pp + En; DS.d[1] = ei_bp + En; DS.d[2] = ei_bb + En;
  DS.s[0] = ei_pp;      DS.s[1] = ei_bp;      DS.s[2] = ei_bb;
  zero_int_kernel<<<cdiv(NCAT, 256), B, 0, stream>>>(cnt_cat, NCAT);
  hist_all_kernel<<<cdiv(3 * En, 256), B, 0, stream>>>(DS, cnt_cat);
  scan1_kernel<<<NB_TOT, B, 0, stream>>>(cnt_cat, offs_cat, bsum, NCAT);
  scan2_kernel<<<3, B, 0, stream>>>(bsum);
  scan3_kernel<<<NB_TOT, B, 0, stream>>>(cnt_cat, offs_cat, bsum, NCAT);
  copy_int_kernel<<<cdiv(NCAT, 256), B, 0, stream>>>(offs_cat, cnt_cat, NCAT);
  scatter_all_kernel<<<cdiv(3 * En, 256), B, 0, stream>>>(DS, cnt_cat, srcs_cat, pos_cat);

  const int* offs_pp = offs_cat + OFF_PP;
  const int* offs_bp = offs_cat + OFF_BP;
  const int* offs_bb = offs_cat + OFF_BB;
  const int* srcs_pp = srcs_cat;
  const int* srcs_bp = srcs_cat + En;
  const int* srcs_bb = srcs_cat + 2 * En;

  EdgeJobs EJ;
  EJ.EA[0] = ea_pp; EJ.We[0] = W_edge_pp; EJ.be[0] = b_edge_pp;
  EJ.wa1[0] = wa_pp1; EJ.wa2[0] = wa_pp2; EJ.hd1[0] = hd_pp1; EJ.hd2[0] = hd_pp2;
  EJ.pos[0] = pos_cat;
  EJ.EA[1] = ea_bb; EJ.We[1] = W_edge_bb; EJ.be[1] = b_edge_bb;
  EJ.wa1[1] = wa_bb1; EJ.wa2[1] = nullptr; EJ.hd1[1] = hd_bb1; EJ.hd2[1] = nullptr;
  EJ.pos[1] = pos_cat + 2 * En;
  EJ.EA[2] = ea_bp; EJ.We[2] = W_edge_bp; EJ.be[2] = b_edge_bp;
  EJ.wa1[2] = wa_bp1; EJ.wa2[2] = wa_bp2; EJ.hd1[2] = hd_bp1; EJ.hd2[2] = hd_bp2;
  EJ.pos[2] = pos_cat + En;
  edge_fused_kernel<<<3 * 512, B, 0, stream>>>(EJ, sacc);

  selfscale_kernel<<<1, 64, 0, stream>>>(sacc, invE, self_pp1, self_pp2, self_bb1);

  // ---- conv1 ----
  hgemm_kernel<<<cdiv(NPn, 64), B, 0, stream>>>(xp, c1_pp_W, c1_pp_asrc, c1_pp_adst,
      wd1, xp, sA_src, sA_dst, sB_dst, NPn);
  hgemm2_kernel<<<cdiv(NBn, 64), B, 0, stream>>>(hbuf, c1_bp_Wsrc, c1_bp_asrc,
      c1_bb_W, c1_bb_asrc, c1_bb_adst, b1v, sB_src, sC_src, sC_dst, NBn);
  gat_row2_kernel<<<cdiv(NPn * 64, 256), B, 0, stream>>>(
      offs_pp, srcs_pp, sA_src, sA_dst, hd_pp1, self_pp1, xp, c1_pp_bias,
      offs_bp, srcs_bp, sB_src, sB_dst, hd_bp1, b1v, c1_bp_bias, p1, NPn);
  gat_row_kernel<<<cdiv(NBn * 64, 256), B, 0, stream>>>(offs_bb, srcs_bb, sC_src, sC_dst,
      hd_bb1, self_bb1, hbuf, c1_bb_bias, b1v, NBn);

  // ---- conv2 (head fused) ----
  hgemm_kernel<<<cdiv(NPn, 64), B, 0, stream>>>(p1, c2_pp_W, c2_pp_asrc, c2_pp_adst,
      wd2, hbuf, sA_src, sA_dst, sB_dst, NPn);
  hgemm_kernel<<<cdiv(NBn, 64), B, 0, stream>>>(b1v, c2_bp_Wsrc, c2_bp_asrc, nullptr,
      nullptr, b1v, sB_src, nullptr, nullptr, NBn);
  gat_row2h_kernel<<<cdiv(NPn * 64, 256), B, 0, stream>>>(
      offs_pp, srcs_pp, sA_src, sA_dst, hd_pp2, self_pp2, hbuf, c2_pp_bias,
      offs_bp, srcs_bp, sB_src, sB_dst, hd_bp2, b1v, c2_bp_bias,
      W_out, b_out, (float*)d_out, NPn);
}